// Round 1
// baseline (438.552 us; speedup 1.0000x reference)
//
#include <hip/hip_runtime.h>

#define D 128

// ---------------- CSR build ----------------

__global__ void count_kernel(const int* __restrict__ dst, int* __restrict__ counts, int E) {
    int e = blockIdx.x * blockDim.x + threadIdx.x;
    if (e < E) atomicAdd(&counts[dst[e]], 1);
}

__global__ void scan_kernel(const int* __restrict__ counts, int* __restrict__ offsets, int n) {
    __shared__ int sums[256];
    int t = threadIdx.x;
    int chunk = (n + 255) / 256;
    int lo = t * chunk;
    int hi = lo + chunk; if (hi > n) hi = n; if (lo > n) lo = n;
    int s = 0;
    for (int i = lo; i < hi; ++i) s += counts[i];
    sums[t] = s;
    __syncthreads();
    // Hillis-Steele inclusive scan over 256 partials
    for (int d = 1; d < 256; d <<= 1) {
        int v = (t >= d) ? sums[t - d] : 0;
        __syncthreads();
        sums[t] += v;
        __syncthreads();
    }
    int run = (t == 0) ? 0 : sums[t - 1];
    for (int i = lo; i < hi; ++i) { offsets[i] = run; run += counts[i]; }
    if (t == 255) offsets[n] = run;
}

__global__ void fill_kernel(const int* __restrict__ src, const int* __restrict__ dst,
                            const int* __restrict__ offsets, int* __restrict__ cursor,
                            int* __restrict__ csr, int E) {
    int e = blockIdx.x * blockDim.x + threadIdx.x;
    if (e < E) {
        int d = dst[e];
        int p = atomicAdd(&cursor[d], 1);
        csr[offsets[d] + p] = src[e];
    }
}

// ---------------- mean aggregation (gather over CSR) ----------------
// 8 nodes per 256-thread block; 32 lanes x float4 cover one 128-ch row.

__global__ void aggregate_kernel(const float* __restrict__ xin, const int* __restrict__ offsets,
                                 const int* __restrict__ csr, float* __restrict__ agg, int nnodes) {
    int node = blockIdx.x * 8 + (threadIdx.x >> 5);
    int c4 = threadIdx.x & 31;
    if (node >= nnodes) return;
    int lo = offsets[node], hi = offsets[node + 1];
    float ax = 0.f, ay = 0.f, az = 0.f, aw = 0.f;
    for (int k = lo; k < hi; ++k) {
        int s = csr[k];  // broadcast across the 32 lanes of this node-group
        const float4 v = *reinterpret_cast<const float4*>(xin + (size_t)s * D + (c4 << 2));
        ax += v.x; ay += v.y; az += v.z; aw += v.w;
    }
    float inv = 1.0f / fmaxf((float)(hi - lo), 1.0f);
    float4 r; r.x = ax * inv; r.y = ay * inv; r.z = az * inv; r.w = aw * inv;
    *reinterpret_cast<float4*>(agg + (size_t)node * D + (c4 << 2)) = r;
}

// ---------------- fused SAGE linear: out = l2norm(agg@Wl + b + x@Wr), opt ReLU ----------------
// Block: 256 threads, 32 nodes. LDS holds transposed agg/x tiles so the inner
// loop is 2x ds_read_b128 + 2x global float4 per 32 FMAs. Thread (tx,ty)
// computes a 4-node x 4-channel micro-tile.

template <bool RELU>
__global__ __launch_bounds__(256) void sage_linear_kernel(
    const float* __restrict__ agg, const float* __restrict__ xin,
    const float* __restrict__ Wl, const float* __restrict__ bl,
    const float* __restrict__ Wr, float* __restrict__ out, int nnodes) {

    __shared__ float aT[128][36];  // [channel][node], pad 36 keeps float4 alignment
    __shared__ float xT[128][36];

    const int t  = threadIdx.x;
    const int nb = blockIdx.x * 32;

    // --- stage + transpose: each thread loads 4 rows' float4 at channel c4, writes 4 transposed float4 ---
    {
        const int n4 = t >> 5;   // node group 0..7 -> nodes n4*4..+3
        const int c4 = t & 31;   // float4 index within row
        float ra[4][4], rx[4][4];
        for (int i = 0; i < 4; ++i) {
            int gn = nb + n4 * 4 + i;
            float4 va = make_float4(0.f, 0.f, 0.f, 0.f);
            float4 vx = make_float4(0.f, 0.f, 0.f, 0.f);
            if (gn < nnodes) {
                va = *reinterpret_cast<const float4*>(agg + (size_t)gn * D + (c4 << 2));
                vx = *reinterpret_cast<const float4*>(xin + (size_t)gn * D + (c4 << 2));
            }
            ra[i][0] = va.x; ra[i][1] = va.y; ra[i][2] = va.z; ra[i][3] = va.w;
            rx[i][0] = vx.x; rx[i][1] = vx.y; rx[i][2] = vx.z; rx[i][3] = vx.w;
        }
        for (int j = 0; j < 4; ++j) {
            *reinterpret_cast<float4*>(&aT[c4 * 4 + j][n4 * 4]) =
                make_float4(ra[0][j], ra[1][j], ra[2][j], ra[3][j]);
            *reinterpret_cast<float4*>(&xT[c4 * 4 + j][n4 * 4]) =
                make_float4(rx[0][j], rx[1][j], rx[2][j], rx[3][j]);
        }
    }
    __syncthreads();

    const int tx = t & 31;        // channel group: j0..j0+3
    const int ty = t >> 5;        // node group: n0..n0+3
    const int j0 = tx * 4;
    const int n0 = ty * 4;

    float acc[4][4];
    {
        const float4 bv = *reinterpret_cast<const float4*>(bl + j0);
        for (int n = 0; n < 4; ++n) { acc[n][0] = bv.x; acc[n][1] = bv.y; acc[n][2] = bv.z; acc[n][3] = bv.w; }
    }

#pragma unroll 4
    for (int c = 0; c < 128; ++c) {
        const float4 wl = *reinterpret_cast<const float4*>(Wl + c * D + j0);
        const float4 wr = *reinterpret_cast<const float4*>(Wr + c * D + j0);
        const float4 av = *reinterpret_cast<const float4*>(&aT[c][n0]);
        const float4 xv = *reinterpret_cast<const float4*>(&xT[c][n0]);
        const float a[4] = {av.x, av.y, av.z, av.w};
        const float x[4] = {xv.x, xv.y, xv.z, xv.w};
        const float wlv[4] = {wl.x, wl.y, wl.z, wl.w};
        const float wrv[4] = {wr.x, wr.y, wr.z, wr.w};
        for (int n = 0; n < 4; ++n)
            for (int j = 0; j < 4; ++j)
                acc[n][j] = fmaf(a[n], wlv[j], fmaf(x[n], wrv[j], acc[n][j]));
    }

    // --- l2 normalize per node row: reduce sum-of-squares across the 32 tx lanes ---
    float ss[4];
    for (int n = 0; n < 4; ++n) {
        ss[n] = 0.f;
        for (int j = 0; j < 4; ++j) ss[n] += acc[n][j] * acc[n][j];
    }
    for (int m = 1; m < 32; m <<= 1)
        for (int n = 0; n < 4; ++n) ss[n] += __shfl_xor(ss[n], m, 64);

    for (int n = 0; n < 4; ++n) {
        int gn = nb + n0 + n;
        if (gn >= nnodes) continue;
        float scale = 1.0f / fmaxf(sqrtf(ss[n]), 1e-12f);
        float4 r;
        r.x = acc[n][0] * scale; r.y = acc[n][1] * scale;
        r.z = acc[n][2] * scale; r.w = acc[n][3] * scale;
        if (RELU) {
            r.x = fmaxf(r.x, 0.f); r.y = fmaxf(r.y, 0.f);
            r.z = fmaxf(r.z, 0.f); r.w = fmaxf(r.w, 0.f);
        }
        *reinterpret_cast<float4*>(out + (size_t)gn * D + j0) = r;
    }
}

// ---------------- head: logits = h@Wfc + bfc, softmax over 2 classes ----------------
// One 64-lane wave per node.

__global__ void head_kernel(const float* __restrict__ h, const float* __restrict__ Wfc,
                            const float* __restrict__ bfc, float* __restrict__ out, int nnodes) {
    int wid  = (blockIdx.x * blockDim.x + threadIdx.x) >> 6;
    int lane = threadIdx.x & 63;
    if (wid >= nnodes) return;
    float v0 = h[(size_t)wid * D + lane];
    float v1 = h[(size_t)wid * D + 64 + lane];
    float d0 = v0 * Wfc[lane * 2]       + v1 * Wfc[(lane + 64) * 2];
    float d1 = v0 * Wfc[lane * 2 + 1]   + v1 * Wfc[(lane + 64) * 2 + 1];
    for (int m = 1; m < 64; m <<= 1) {
        d0 += __shfl_xor(d0, m, 64);
        d1 += __shfl_xor(d1, m, 64);
    }
    if (lane == 0) {
        d0 += bfc[0]; d1 += bfc[1];
        float mx = fmaxf(d0, d1);
        float e0 = expf(d0 - mx), e1 = expf(d1 - mx);
        float inv = 1.0f / (e0 + e1);
        out[(size_t)wid * 2]     = e0 * inv;
        out[(size_t)wid * 2 + 1] = e1 * inv;
    }
}

// ---------------- launch ----------------

extern "C" void kernel_launch(void* const* d_in, const int* in_sizes, int n_in,
                              void* d_out, int out_size, void* d_ws, size_t ws_size,
                              hipStream_t stream) {
    const float* x   = (const float*)d_in[0];
    const int*   ei  = (const int*)d_in[1];
    const float* W1l = (const float*)d_in[2];
    const float* b1l = (const float*)d_in[3];
    const float* W1r = (const float*)d_in[4];
    const float* W2l = (const float*)d_in[5];
    const float* b2l = (const float*)d_in[6];
    const float* W2r = (const float*)d_in[7];
    const float* Wfc = (const float*)d_in[8];
    const float* bfc = (const float*)d_in[9];

    const int N = in_sizes[0] / D;
    const int E = in_sizes[1] / 2;
    const int* src = ei;        // edge_index[0]
    const int* dst = ei + E;    // edge_index[1]

    // workspace layout (floats first for 16B alignment)
    float* agg = (float*)d_ws;                       // N*128
    float* h1  = agg + (size_t)N * D;                // N*128
    int* counts  = (int*)(h1 + (size_t)N * D);       // N
    int* offsets = counts + N;                       // N+1
    int* cursor  = offsets + N + 1;                  // N
    int* csr     = cursor + N;                       // E

    hipMemsetAsync(counts, 0, (size_t)(3 * N + 1) * sizeof(int), stream);

    count_kernel<<<(E + 255) / 256, 256, 0, stream>>>(dst, counts, E);
    scan_kernel<<<1, 256, 0, stream>>>(counts, offsets, N);
    fill_kernel<<<(E + 255) / 256, 256, 0, stream>>>(src, dst, offsets, cursor, csr, E);

    // layer 1
    aggregate_kernel<<<(N + 7) / 8, 256, 0, stream>>>(x, offsets, csr, agg, N);
    sage_linear_kernel<true><<<(N + 31) / 32, 256, 0, stream>>>(agg, x, W1l, b1l, W1r, h1, N);

    // layer 2 (output overwrites agg in place; block-local read-before-write)
    aggregate_kernel<<<(N + 7) / 8, 256, 0, stream>>>(h1, offsets, csr, agg, N);
    sage_linear_kernel<false><<<(N + 31) / 32, 256, 0, stream>>>(agg, h1, W2l, b2l, W2r, agg, N);

    // head + softmax
    head_kernel<<<(N + 3) / 4, 256, 0, stream>>>(agg, Wfc, bfc, (float*)d_out, N);
}

// Round 2
// 358.000 us; speedup vs baseline: 1.2250x; 1.2250x over previous
//
#include <hip/hip_runtime.h>

#define D 128

// ---------------- CSR build ----------------

__global__ void count_kernel(const int* __restrict__ dst, int* __restrict__ counts, int E) {
    int e = blockIdx.x * blockDim.x + threadIdx.x;
    if (e < E) atomicAdd(&counts[dst[e]], 1);
}

// Multi-block scan: 256 threads x 4 elements = 1024/block.
// scan_part: per-block total -> partials[b]
__global__ void scan_part_kernel(const int* __restrict__ counts, int* __restrict__ partials, int n) {
    __shared__ int lds[256];
    int t = threadIdx.x;
    int base = blockIdx.x * 1024 + t * 4;
    int s = 0;
    if (base + 3 < n) {
        int4 v = *reinterpret_cast<const int4*>(counts + base);
        s = v.x + v.y + v.z + v.w;
    } else {
        for (int i = 0; i < 4; ++i) if (base + i < n) s += counts[base + i];
    }
    lds[t] = s;
    __syncthreads();
    for (int d = 128; d > 0; d >>= 1) { if (t < d) lds[t] += lds[t + d]; __syncthreads(); }
    if (t == 0) partials[blockIdx.x] = lds[0];
}

// scan_base: single block scans <=256 partials in place to exclusive bases; writes offsets[n]=total
__global__ void scan_base_kernel(int* __restrict__ partials, int nb, int* __restrict__ offsets, int n) {
    __shared__ int lds[256];
    int t = threadIdx.x;
    int v = (t < nb) ? partials[t] : 0;
    lds[t] = v;
    __syncthreads();
    for (int d = 1; d < 256; d <<= 1) {
        int u = (t >= d) ? lds[t - d] : 0;
        __syncthreads();
        lds[t] += u;
        __syncthreads();
    }
    if (t < nb) partials[t] = lds[t] - v;   // exclusive base
    if (t == 255) offsets[n] = lds[255];    // grand total
}

// scan_write: per-block exclusive scan + base -> offsets
__global__ void scan_write_kernel(const int* __restrict__ counts, const int* __restrict__ partials,
                                  int* __restrict__ offsets, int n) {
    __shared__ int lds[256];
    int t = threadIdx.x;
    int base = blockIdx.x * 1024 + t * 4;
    int v[4];
    for (int i = 0; i < 4; ++i) v[i] = (base + i < n) ? counts[base + i] : 0;
    int s = v[0] + v[1] + v[2] + v[3];
    lds[t] = s;
    __syncthreads();
    for (int d = 1; d < 256; d <<= 1) {
        int u = (t >= d) ? lds[t - d] : 0;
        __syncthreads();
        lds[t] += u;
        __syncthreads();
    }
    int run = (t == 0 ? 0 : lds[t - 1]) + partials[blockIdx.x];
    for (int i = 0; i < 4; ++i) {
        if (base + i < n) offsets[base + i] = run;
        run += v[i];
    }
}

__global__ void fill_kernel(const int* __restrict__ src, const int* __restrict__ dst,
                            const int* __restrict__ offsets, int* __restrict__ cursor,
                            int* __restrict__ csr, int E) {
    int e = blockIdx.x * blockDim.x + threadIdx.x;
    if (e < E) {
        int d = dst[e];
        int p = atomicAdd(&cursor[d], 1);
        csr[offsets[d] + p] = src[e];
    }
}

// ---------------- mean aggregation (gather over CSR) ----------------
// 8 nodes per 256-thread block; 32 lanes x float4 cover one 128-ch row.

__global__ void aggregate_kernel(const float* __restrict__ xin, const int* __restrict__ offsets,
                                 const int* __restrict__ csr, float* __restrict__ agg, int nnodes) {
    int node = blockIdx.x * 8 + (threadIdx.x >> 5);
    int c4 = threadIdx.x & 31;
    if (node >= nnodes) return;
    int lo = offsets[node], hi = offsets[node + 1];
    float ax = 0.f, ay = 0.f, az = 0.f, aw = 0.f;
    for (int k = lo; k < hi; ++k) {
        int s = csr[k];  // broadcast across the 32 lanes of this node-group
        const float4 v = *reinterpret_cast<const float4*>(xin + (size_t)s * D + (c4 << 2));
        ax += v.x; ay += v.y; az += v.z; aw += v.w;
    }
    float inv = 1.0f / fmaxf((float)(hi - lo), 1.0f);
    float4 r; r.x = ax * inv; r.y = ay * inv; r.z = az * inv; r.w = aw * inv;
    *reinterpret_cast<float4*>(agg + (size_t)node * D + (c4 << 2)) = r;
}

// ---------------- fused SAGE linear: out = l2norm(agg@Wl + b + x@Wr), opt ReLU ----------------

template <bool RELU>
__global__ __launch_bounds__(256) void sage_linear_kernel(
    const float* __restrict__ agg, const float* __restrict__ xin,
    const float* __restrict__ Wl, const float* __restrict__ bl,
    const float* __restrict__ Wr, float* __restrict__ out, int nnodes) {

    __shared__ float aT[128][36];  // [channel][node], pad 36 keeps float4 alignment
    __shared__ float xT[128][36];

    const int t  = threadIdx.x;
    const int nb = blockIdx.x * 32;

    // --- stage + transpose ---
    {
        const int n4 = t >> 5;   // node group 0..7 -> nodes n4*4..+3
        const int c4 = t & 31;   // float4 index within row
        float ra[4][4], rx[4][4];
        for (int i = 0; i < 4; ++i) {
            int gn = nb + n4 * 4 + i;
            float4 va = make_float4(0.f, 0.f, 0.f, 0.f);
            float4 vx = make_float4(0.f, 0.f, 0.f, 0.f);
            if (gn < nnodes) {
                va = *reinterpret_cast<const float4*>(agg + (size_t)gn * D + (c4 << 2));
                vx = *reinterpret_cast<const float4*>(xin + (size_t)gn * D + (c4 << 2));
            }
            ra[i][0] = va.x; ra[i][1] = va.y; ra[i][2] = va.z; ra[i][3] = va.w;
            rx[i][0] = vx.x; rx[i][1] = vx.y; rx[i][2] = vx.z; rx[i][3] = vx.w;
        }
        for (int j = 0; j < 4; ++j) {
            *reinterpret_cast<float4*>(&aT[c4 * 4 + j][n4 * 4]) =
                make_float4(ra[0][j], ra[1][j], ra[2][j], ra[3][j]);
            *reinterpret_cast<float4*>(&xT[c4 * 4 + j][n4 * 4]) =
                make_float4(rx[0][j], rx[1][j], rx[2][j], rx[3][j]);
        }
    }
    __syncthreads();

    const int tx = t & 31;        // channel group: j0..j0+3
    const int ty = t >> 5;        // node group: n0..n0+3
    const int j0 = tx * 4;
    const int n0 = ty * 4;

    float acc[4][4];
    {
        const float4 bv = *reinterpret_cast<const float4*>(bl + j0);
        for (int n = 0; n < 4; ++n) { acc[n][0] = bv.x; acc[n][1] = bv.y; acc[n][2] = bv.z; acc[n][3] = bv.w; }
    }

#pragma unroll 4
    for (int c = 0; c < 128; ++c) {
        const float4 wl = *reinterpret_cast<const float4*>(Wl + c * D + j0);
        const float4 wr = *reinterpret_cast<const float4*>(Wr + c * D + j0);
        const float4 av = *reinterpret_cast<const float4*>(&aT[c][n0]);
        const float4 xv = *reinterpret_cast<const float4*>(&xT[c][n0]);
        const float a[4] = {av.x, av.y, av.z, av.w};
        const float x[4] = {xv.x, xv.y, xv.z, xv.w};
        const float wlv[4] = {wl.x, wl.y, wl.z, wl.w};
        const float wrv[4] = {wr.x, wr.y, wr.z, wr.w};
        for (int n = 0; n < 4; ++n)
            for (int j = 0; j < 4; ++j)
                acc[n][j] = fmaf(a[n], wlv[j], fmaf(x[n], wrv[j], acc[n][j]));
    }

    // --- l2 normalize per node row ---
    float ss[4];
    for (int n = 0; n < 4; ++n) {
        ss[n] = 0.f;
        for (int j = 0; j < 4; ++j) ss[n] += acc[n][j] * acc[n][j];
    }
    for (int m = 1; m < 32; m <<= 1)
        for (int n = 0; n < 4; ++n) ss[n] += __shfl_xor(ss[n], m, 64);

    for (int n = 0; n < 4; ++n) {
        int gn = nb + n0 + n;
        if (gn >= nnodes) continue;
        float scale = 1.0f / fmaxf(sqrtf(ss[n]), 1e-12f);
        float4 r;
        r.x = acc[n][0] * scale; r.y = acc[n][1] * scale;
        r.z = acc[n][2] * scale; r.w = acc[n][3] * scale;
        if (RELU) {
            r.x = fmaxf(r.x, 0.f); r.y = fmaxf(r.y, 0.f);
            r.z = fmaxf(r.z, 0.f); r.w = fmaxf(r.w, 0.f);
        }
        *reinterpret_cast<float4*>(out + (size_t)gn * D + j0) = r;
    }
}

// ---------------- head: logits = h@Wfc + bfc, softmax over 2 classes ----------------

__global__ void head_kernel(const float* __restrict__ h, const float* __restrict__ Wfc,
                            const float* __restrict__ bfc, float* __restrict__ out, int nnodes) {
    int wid  = (blockIdx.x * blockDim.x + threadIdx.x) >> 6;
    int lane = threadIdx.x & 63;
    if (wid >= nnodes) return;
    float v0 = h[(size_t)wid * D + lane];
    float v1 = h[(size_t)wid * D + 64 + lane];
    float d0 = v0 * Wfc[lane * 2]       + v1 * Wfc[(lane + 64) * 2];
    float d1 = v0 * Wfc[lane * 2 + 1]   + v1 * Wfc[(lane + 64) * 2 + 1];
    for (int m = 1; m < 64; m <<= 1) {
        d0 += __shfl_xor(d0, m, 64);
        d1 += __shfl_xor(d1, m, 64);
    }
    if (lane == 0) {
        d0 += bfc[0]; d1 += bfc[1];
        float mx = fmaxf(d0, d1);
        float e0 = expf(d0 - mx), e1 = expf(d1 - mx);
        float inv = 1.0f / (e0 + e1);
        out[(size_t)wid * 2]     = e0 * inv;
        out[(size_t)wid * 2 + 1] = e1 * inv;
    }
}

// ---------------- launch ----------------

extern "C" void kernel_launch(void* const* d_in, const int* in_sizes, int n_in,
                              void* d_out, int out_size, void* d_ws, size_t ws_size,
                              hipStream_t stream) {
    const float* x   = (const float*)d_in[0];
    const int*   ei  = (const int*)d_in[1];
    const float* W1l = (const float*)d_in[2];
    const float* b1l = (const float*)d_in[3];
    const float* W1r = (const float*)d_in[4];
    const float* W2l = (const float*)d_in[5];
    const float* b2l = (const float*)d_in[6];
    const float* W2r = (const float*)d_in[7];
    const float* Wfc = (const float*)d_in[8];
    const float* bfc = (const float*)d_in[9];

    const int N = in_sizes[0] / D;
    const int E = in_sizes[1] / 2;
    const int* src = ei;        // edge_index[0]
    const int* dst = ei + E;    // edge_index[1]

    // workspace layout (floats first for 16B alignment)
    float* agg = (float*)d_ws;                       // N*128
    float* h1  = agg + (size_t)N * D;                // N*128
    int* counts  = (int*)(h1 + (size_t)N * D);       // N
    int* offsets = counts + N;                       // N+1
    int* cursor  = offsets + N + 1;                  // N
    int* csr     = cursor + N;                       // E
    int* partials = csr + E;                         // <=256

    const int nb_scan = (N + 1023) / 1024;           // 49 for N=50000 (<=256 required)

    hipMemsetAsync(counts, 0, (size_t)(3 * N + 1) * sizeof(int), stream);

    count_kernel<<<(E + 255) / 256, 256, 0, stream>>>(dst, counts, E);
    scan_part_kernel<<<nb_scan, 256, 0, stream>>>(counts, partials, N);
    scan_base_kernel<<<1, 256, 0, stream>>>(partials, nb_scan, offsets, N);
    scan_write_kernel<<<nb_scan, 256, 0, stream>>>(counts, partials, offsets, N);
    fill_kernel<<<(E + 255) / 256, 256, 0, stream>>>(src, dst, offsets, cursor, csr, E);

    // layer 1
    aggregate_kernel<<<(N + 7) / 8, 256, 0, stream>>>(x, offsets, csr, agg, N);
    sage_linear_kernel<true><<<(N + 31) / 32, 256, 0, stream>>>(agg, x, W1l, b1l, W1r, h1, N);

    // layer 2 (output overwrites agg in place; block-local read-before-write)
    aggregate_kernel<<<(N + 7) / 8, 256, 0, stream>>>(h1, offsets, csr, agg, N);
    sage_linear_kernel<false><<<(N + 31) / 32, 256, 0, stream>>>(agg, h1, W2l, b2l, W2r, agg, N);

    // head + softmax
    head_kernel<<<(N + 3) / 4, 256, 0, stream>>>(agg, Wfc, bfc, (float*)d_out, N);
}

// Round 3
// 260.561 us; speedup vs baseline: 1.6831x; 1.3740x over previous
//
#include <hip/hip_runtime.h>

#define D 128

typedef __attribute__((ext_vector_type(8))) short short8;
typedef __attribute__((ext_vector_type(4))) float f32x4;

__device__ __forceinline__ unsigned short f2b(float f) {
    unsigned u = __builtin_bit_cast(unsigned, f);
    u += 0x7fffu + ((u >> 16) & 1u);           // round-to-nearest-even
    return (unsigned short)(u >> 16);
}
__device__ __forceinline__ float b2f(unsigned short b) {
    unsigned u = ((unsigned)b) << 16;
    return __builtin_bit_cast(float, u);
}

// ---------------- CSR build ----------------

__global__ void count_kernel(const int* __restrict__ dst, int* __restrict__ counts, int E) {
    int e = blockIdx.x * blockDim.x + threadIdx.x;
    if (e < E) atomicAdd(&counts[dst[e]], 1);
}

__global__ void scan_part_kernel(const int* __restrict__ counts, int* __restrict__ partials, int n) {
    __shared__ int lds[256];
    int t = threadIdx.x;
    int base = blockIdx.x * 1024 + t * 4;
    int s = 0;
    if (base + 3 < n) {
        int4 v = *reinterpret_cast<const int4*>(counts + base);
        s = v.x + v.y + v.z + v.w;
    } else {
        for (int i = 0; i < 4; ++i) if (base + i < n) s += counts[base + i];
    }
    lds[t] = s;
    __syncthreads();
    for (int d = 128; d > 0; d >>= 1) { if (t < d) lds[t] += lds[t + d]; __syncthreads(); }
    if (t == 0) partials[blockIdx.x] = lds[0];
}

__global__ void scan_base_kernel(int* __restrict__ partials, int nb, int* __restrict__ offsets, int n) {
    __shared__ int lds[256];
    int t = threadIdx.x;
    int v = (t < nb) ? partials[t] : 0;
    lds[t] = v;
    __syncthreads();
    for (int d = 1; d < 256; d <<= 1) {
        int u = (t >= d) ? lds[t - d] : 0;
        __syncthreads();
        lds[t] += u;
        __syncthreads();
    }
    if (t < nb) partials[t] = lds[t] - v;
    if (t == 255) offsets[n] = lds[255];
}

__global__ void scan_write_kernel(const int* __restrict__ counts, const int* __restrict__ partials,
                                  int* __restrict__ offsets, int n) {
    __shared__ int lds[256];
    int t = threadIdx.x;
    int base = blockIdx.x * 1024 + t * 4;
    int v[4];
    for (int i = 0; i < 4; ++i) v[i] = (base + i < n) ? counts[base + i] : 0;
    int s = v[0] + v[1] + v[2] + v[3];
    lds[t] = s;
    __syncthreads();
    for (int d = 1; d < 256; d <<= 1) {
        int u = (t >= d) ? lds[t - d] : 0;
        __syncthreads();
        lds[t] += u;
        __syncthreads();
    }
    int run = (t == 0 ? 0 : lds[t - 1]) + partials[blockIdx.x];
    for (int i = 0; i < 4; ++i) {
        if (base + i < n) offsets[base + i] = run;
        run += v[i];
    }
}

__global__ void fill_kernel(const int* __restrict__ src, const int* __restrict__ dst,
                            const int* __restrict__ offsets, int* __restrict__ cursor,
                            int* __restrict__ csr, int E) {
    int e = blockIdx.x * blockDim.x + threadIdx.x;
    if (e < E) {
        int d = dst[e];
        int p = atomicAdd(&cursor[d], 1);
        csr[offsets[d] + p] = src[e];
    }
}

// ---------------- bf16 prep ----------------

// x (f32, N x 128) -> Acat1[n][128..255] (bf16, row stride 256)
__global__ void cast_x_kernel(const float* __restrict__ x, unsigned short* __restrict__ acat, int n16) {
    int g = blockIdx.x * blockDim.x + threadIdx.x;   // one 8-elem chunk
    if (g >= n16) return;
    int row = g >> 4, chunk = g & 15;
    const float4 v0 = *reinterpret_cast<const float4*>(x + (size_t)g * 8);
    const float4 v1 = *reinterpret_cast<const float4*>(x + (size_t)g * 8 + 4);
    short8 r;
    r[0] = (short)f2b(v0.x); r[1] = (short)f2b(v0.y); r[2] = (short)f2b(v0.z); r[3] = (short)f2b(v0.w);
    r[4] = (short)f2b(v1.x); r[5] = (short)f2b(v1.y); r[6] = (short)f2b(v1.z); r[7] = (short)f2b(v1.w);
    *reinterpret_cast<short8*>(acat + (size_t)row * 256 + 128 + chunk * 8) = r;
}

// WT[j][k] = (k<128 ? Wl[k][j] : Wr[k-128][j]) as bf16; 2 layers in one launch (256 blocks)
__global__ void prep_w_kernel(const float* __restrict__ W1l, const float* __restrict__ W1r,
                              const float* __restrict__ W2l, const float* __restrict__ W2r,
                              unsigned short* __restrict__ WT1, unsigned short* __restrict__ WT2) {
    int layer = blockIdx.x >> 7;
    int j = blockIdx.x & 127;
    int k = threadIdx.x;  // 0..255
    const float* Wl = layer ? W2l : W1l;
    const float* Wr = layer ? W2r : W1r;
    unsigned short* WT = layer ? WT2 : WT1;
    float v = (k < 128) ? Wl[k * D + j] : Wr[(k - 128) * D + j];
    WT[(size_t)j * 256 + k] = f2b(v);
}

// ---------------- mean aggregation (bf16 gather, f32 accumulate) ----------------
// 16 nodes/block; 16 lanes x 16B cover one 256B row.

__global__ void aggregate_kernel(const unsigned short* __restrict__ xin,   // row stride 256 (pre-offset +128)
                                 const int* __restrict__ offsets, const int* __restrict__ csr,
                                 unsigned short* __restrict__ out,         // row stride 256 (offset 0)
                                 int nnodes) {
    int node = blockIdx.x * 16 + (threadIdx.x >> 4);
    int l16 = threadIdx.x & 15;
    if (node >= nnodes) return;
    int lo = offsets[node], hi = offsets[node + 1];
    float acc[8] = {0.f, 0.f, 0.f, 0.f, 0.f, 0.f, 0.f, 0.f};
    for (int k = lo; k < hi; ++k) {
        int s = csr[k];
        const short8 v = *reinterpret_cast<const short8*>(xin + (size_t)s * 256 + l16 * 8);
        for (int i = 0; i < 8; ++i) acc[i] += b2f((unsigned short)v[i]);
    }
    float inv = 1.0f / fmaxf((float)(hi - lo), 1.0f);
    short8 r;
    for (int i = 0; i < 8; ++i) r[i] = (short)f2b(acc[i] * inv);
    *reinterpret_cast<short8*>(out + (size_t)node * 256 + l16 * 8) = r;
}

// ---------------- fused SAGE linear via MFMA ----------------
// out[n][0..127] = l2norm(Acat[n][0..255] @ Wcat + b), opt ReLU; K=256.
// Block = 4 waves x 16 rows. Per wave: 8 col-tiles x 8 k-steps of mfma_f32_16x16x32_bf16.
// A frag: lane l reads Acat[rowbase+(l&15)][ks*32+(l>>4)*8 ..+7]  (16B contiguous)
// B frag: lane l reads WT[j*16+(l&15)][ks*32+(l>>4)*8 ..+7]       (WT = Wcat^T)
// C/D:    col=lane&15, row=(lane>>4)*4+reg   [m89-verified]

template <bool RELU>
__global__ __launch_bounds__(256) void sage_mfma_kernel(
    const unsigned short* __restrict__ Acat, const unsigned short* __restrict__ WT,
    const float* __restrict__ bias, unsigned short* __restrict__ out,
    int out_stride, int nnodes) {

    const int tid = threadIdx.x;
    const int w = tid >> 6, l = tid & 63;
    const int r16 = l & 15, g = l >> 4;
    const int rowbase = blockIdx.x * 64 + w * 16;

    f32x4 acc[8];
#pragma unroll
    for (int j = 0; j < 8; ++j) {
        float bj = bias[j * 16 + r16];
        acc[j] = (f32x4){bj, bj, bj, bj};
    }

    const unsigned short* ap = Acat + (size_t)(rowbase + r16) * 256 + g * 8;
    const unsigned short* bp = WT + (size_t)r16 * 256 + g * 8;

#pragma unroll
    for (int ks = 0; ks < 8; ++ks) {
        const short8 a = *reinterpret_cast<const short8*>(ap + ks * 32);
#pragma unroll
        for (int j = 0; j < 8; ++j) {
            const short8 b = *reinterpret_cast<const short8*>(bp + j * 4096 + ks * 32);
            acc[j] = __builtin_amdgcn_mfma_f32_16x16x32_bf16(a, b, acc[j], 0, 0, 0);
        }
    }

    // l2-norm per output row (row = rowbase + g*4 + i; cols spread over 16 lanes x 8 tiles)
    float ss[4] = {0.f, 0.f, 0.f, 0.f};
#pragma unroll
    for (int j = 0; j < 8; ++j)
#pragma unroll
        for (int i = 0; i < 4; ++i) ss[i] += acc[j][i] * acc[j][i];
#pragma unroll
    for (int m = 1; m < 16; m <<= 1)
#pragma unroll
        for (int i = 0; i < 4; ++i) ss[i] += __shfl_xor(ss[i], m, 64);

#pragma unroll
    for (int i = 0; i < 4; ++i) {
        int row = rowbase + g * 4 + i;
        if (row >= nnodes) continue;
        float sc = 1.0f / fmaxf(sqrtf(ss[i]), 1e-12f);
#pragma unroll
        for (int j = 0; j < 8; ++j) {
            float v = acc[j][i] * sc;
            if (RELU) v = fmaxf(v, 0.f);
            out[(size_t)row * out_stride + j * 16 + r16] = f2b(v);
        }
    }
}

// ---------------- head: logits = h@Wfc + bfc, softmax over 2 classes ----------------

__global__ void head_kernel(const unsigned short* __restrict__ h, const float* __restrict__ Wfc,
                            const float* __restrict__ bfc, float* __restrict__ out, int nnodes) {
    int wid  = (blockIdx.x * blockDim.x + threadIdx.x) >> 6;
    int lane = threadIdx.x & 63;
    if (wid >= nnodes) return;
    float v0 = b2f(h[(size_t)wid * D + lane]);
    float v1 = b2f(h[(size_t)wid * D + 64 + lane]);
    float d0 = v0 * Wfc[lane * 2]       + v1 * Wfc[(lane + 64) * 2];
    float d1 = v0 * Wfc[lane * 2 + 1]   + v1 * Wfc[(lane + 64) * 2 + 1];
    for (int m = 1; m < 64; m <<= 1) {
        d0 += __shfl_xor(d0, m, 64);
        d1 += __shfl_xor(d1, m, 64);
    }
    if (lane == 0) {
        d0 += bfc[0]; d1 += bfc[1];
        float mx = fmaxf(d0, d1);
        float e0 = expf(d0 - mx), e1 = expf(d1 - mx);
        float inv = 1.0f / (e0 + e1);
        out[(size_t)wid * 2]     = e0 * inv;
        out[(size_t)wid * 2 + 1] = e1 * inv;
    }
}

// ---------------- launch ----------------

extern "C" void kernel_launch(void* const* d_in, const int* in_sizes, int n_in,
                              void* d_out, int out_size, void* d_ws, size_t ws_size,
                              hipStream_t stream) {
    const float* x   = (const float*)d_in[0];
    const int*   ei  = (const int*)d_in[1];
    const float* W1l = (const float*)d_in[2];
    const float* b1l = (const float*)d_in[3];
    const float* W1r = (const float*)d_in[4];
    const float* W2l = (const float*)d_in[5];
    const float* b2l = (const float*)d_in[6];
    const float* W2r = (const float*)d_in[7];
    const float* Wfc = (const float*)d_in[8];
    const float* bfc = (const float*)d_in[9];

    const int N = in_sizes[0] / D;
    const int E = in_sizes[1] / 2;
    const int* src = ei;        // edge_index[0]
    const int* dst = ei + E;    // edge_index[1]

    // workspace: bf16 feature tables first (16B aligned), ints after
    unsigned short* Acat1 = (unsigned short*)d_ws;        // N x 256 : [agg1 | xb]
    unsigned short* Acat2 = Acat1 + (size_t)N * 256;      // N x 256 : [agg2 | h1]
    unsigned short* h2    = Acat1;                        // N x 128 (reuses Acat1; gemm2 reads only Acat2)
    unsigned short* WT1   = Acat2 + (size_t)N * 256;      // 128 x 256
    unsigned short* WT2   = WT1 + 128 * 256;              // 128 x 256
    int* counts  = (int*)(WT2 + 128 * 256);               // N
    int* offsets = counts + N;                            // N+1
    int* cursor  = offsets + N + 1;                       // N
    int* csr     = cursor + N;                            // E
    int* partials = csr + E;                              // <=256

    const int nb_scan = (N + 1023) / 1024;

    hipMemsetAsync(counts, 0, (size_t)(3 * N + 1) * sizeof(int), stream);

    // CSR build
    count_kernel<<<(E + 255) / 256, 256, 0, stream>>>(dst, counts, E);
    scan_part_kernel<<<nb_scan, 256, 0, stream>>>(counts, partials, N);
    scan_base_kernel<<<1, 256, 0, stream>>>(partials, nb_scan, offsets, N);
    scan_write_kernel<<<nb_scan, 256, 0, stream>>>(counts, partials, offsets, N);
    fill_kernel<<<(E + 255) / 256, 256, 0, stream>>>(src, dst, offsets, cursor, csr, E);

    // bf16 prep
    cast_x_kernel<<<(N * 16 + 255) / 256, 256, 0, stream>>>(x, Acat1, N * 16);
    prep_w_kernel<<<256, 256, 0, stream>>>(W1l, W1r, W2l, W2r, WT1, WT2);

    // layer 1: agg(xb) -> Acat1[:,0:128]; h1 = l2norm(Acat1@Wcat1+b) -> Acat2[:,128:256]
    aggregate_kernel<<<(N + 15) / 16, 256, 0, stream>>>(Acat1 + 128, offsets, csr, Acat1, N);
    sage_mfma_kernel<true><<<(N + 63) / 64, 256, 0, stream>>>(Acat1, WT1, b1l, Acat2 + 128, 256, N);

    // layer 2: agg(h1) -> Acat2[:,0:128]; h2 = l2norm(Acat2@Wcat2+b) -> h2 (stride 128)
    aggregate_kernel<<<(N + 15) / 16, 256, 0, stream>>>(Acat2 + 128, offsets, csr, Acat2, N);
    sage_mfma_kernel<false><<<(N + 63) / 64, 256, 0, stream>>>(Acat2, WT2, b2l, h2, D, N);

    // head + softmax
    head_kernel<<<(N + 3) / 4, 256, 0, stream>>>(h2, Wfc, bfc, (float*)d_out, N);
}